// Round 9
// baseline (224.351 us; speedup 1.0000x reference)
//
#include <hip/hip_runtime.h>
#include <math.h>

// ---------------------------------------------------------------------------
// BBoxDecoder fp32, round 9.  P=1024, C=512, A=256, D=512, N=1024, NC=30.
//   enc stored [C][P]  => enc_flat[p][c] = enc[c*1024+p]
// R8: 222.2us; top-5 all fillBufferAligned (harness ws re-poison, 42us each).
// Arithmetic: TM2xTN4 GEMMs are LDS-issue-bound (2 ds reads per 8 FMA).
// Fix: TM4xTN4 64x64-tile GEMM body (2 ds reads per 16 FMA) for sprl/awe/
// m1/m2; cls keeps TM2 body. Split-K partial layout unchanged (absmax must
// stay 7.6e-6). Everything else frozen from R8.
// ---------------------------------------------------------------------------

__device__ __forceinline__ float4 ld4(const float* p) {
  return *reinterpret_cast<const float4*>(p);
}
__device__ __forceinline__ void st4(float* p, float4 v) {
  *reinterpret_cast<float4*>(p) = v;
}

// ---- mean[c] = (1/1024) sum_p enc[c][p] -----------------------------------
__global__ void mean_kernel(const float* __restrict__ enc, float* __restrict__ mean) {
  const int c = blockIdx.x, t = threadIdx.x;
  float4 v = reinterpret_cast<const float4*>(enc + (size_t)c * 1024)[t];
  float s = v.x + v.y + v.z + v.w;
  #pragma unroll
  for (int off = 32; off; off >>= 1) s += __shfl_xor(s, off);
  __shared__ float red[4];
  if ((t & 63) == 0) red[t >> 6] = s;
  __syncthreads();
  if (t == 0) mean[c] = (red[0] + red[1] + red[2] + red[3]) * (1.0f / 1024.0f);
}

// ---- h0[d] = mean @ W_init + b_init.  16 blocks x 32 outputs --------------
__global__ __launch_bounds__(256) void h0_k(
    const float* __restrict__ mean, const float* __restrict__ W_init,
    const float* __restrict__ b_init, float* __restrict__ h0) {
  __shared__ float ms[512];
  __shared__ float red[8][33];
  const int t = threadIdx.x;
  ms[t] = mean[t]; ms[t + 256] = mean[t + 256];
  __syncthreads();
  const int d0 = blockIdx.x * 32, dl = t & 31, cg = t >> 5;
  float acc = 0.f;
  #pragma unroll 8
  for (int c = cg * 64; c < cg * 64 + 64; ++c)
    acc += ms[c] * W_init[c * 512 + d0 + dl];
  red[cg][dl] = acc;
  __syncthreads();
  if (t < 32) {
    const float s = red[0][t] + red[1][t] + red[2][t] + red[3][t]
                  + red[4][t] + red[5][t] + red[6][t] + red[7][t];
    h0[d0 + t] = s + b_init[d0 + t];
  }
}

// ---- gh[c] = sigmoid(h0@W_fbeta+b_fbeta)[c]*h0[c];  L[a] = h0@W_lang+b_lang
__global__ __launch_bounds__(256) void ghL_k(
    const float* __restrict__ h0, const float* __restrict__ W_fbeta,
    const float* __restrict__ b_fbeta, const float* __restrict__ W_lang,
    const float* __restrict__ b_lang, float* __restrict__ gh,
    float* __restrict__ Lv) {
  __shared__ float hs[512];
  __shared__ float red[8][33];
  const int t = threadIdx.x;
  hs[t] = h0[t]; hs[t + 256] = h0[t + 256];
  __syncthreads();
  const int b = blockIdx.x, ol = t & 31, cg = t >> 5;
  if (b < 16) {
    const int c0 = b * 32;
    float acc = 0.f;
    #pragma unroll 8
    for (int d = cg * 64; d < cg * 64 + 64; ++d)
      acc += hs[d] * W_fbeta[d * 512 + c0 + ol];
    red[cg][ol] = acc;
    __syncthreads();
    if (t < 32) {
      const int c = c0 + t;
      const float s = red[0][t] + red[1][t] + red[2][t] + red[3][t]
                    + red[4][t] + red[5][t] + red[6][t] + red[7][t] + b_fbeta[c];
      gh[c] = hs[c] / (1.f + __expf(-s));
    }
  } else {
    const int a0 = (b - 16) * 32;
    float acc = 0.f;
    #pragma unroll 8
    for (int d = cg * 64; d < cg * 64 + 64; ++d)
      acc += hs[d] * W_lang[d * 256 + a0 + ol];
    red[cg][ol] = acc;
    __syncthreads();
    if (t < 32) {
      const float s = red[0][t] + red[1][t] + red[2][t] + red[3][t]
                    + red[4][t] + red[5][t] + red[6][t] + red[7][t];
      Lv[a0 + t] = s + b_lang[a0 + t];
    }
  }
}

// ---- OLD GEMM body (TM2xTN4, 32x64 tile) — kept for cls only --------------
template <int AMODE, int BMODE, bool BIAS1, bool NEXACT>
__device__ __forceinline__ void gemm_body2(
    const float* __restrict__ A0, const float* __restrict__ A1,
    const float* __restrict__ A2, const float* __restrict__ A3,
    const float* __restrict__ avec, const float* __restrict__ B,
    const float* __restrict__ bias1, float* __restrict__ C,
    int M, int N, int K, int m0, int n0, int k0, int nsteps,
    float* As, float* Bs) {
  constexpr int LDA = 36, LDB = 68, NA = 8, NB = 16;
  const int tid = threadIdx.x;
  const int tx = tid & 15, ty = tid >> 4;
  float acc[2][4] = {{0.f, 0.f, 0.f, 0.f}, {0.f, 0.f, 0.f, 0.f}};
  float pa[NA], pb[NB];

  auto loadA = [&](int kk0) {
    #pragma unroll
    for (int i = 0; i < NA; ++i) {
      const int idx = tid + i * 256;
      if (AMODE == 1) {
        const int k = idx >> 5, mm = idx & 31;
        pa[i] = A0[(size_t)(kk0 + k) * M + m0 + mm];
      } else {
        const int k = idx & 63, mm = idx >> 6;
        const size_t off = (size_t)(m0 + mm) * K + kk0 + k;
        if (AMODE == 0) {
          pa[i] = A0[off];
        } else {
          float s = A0[off] + A1[off] + A2[off] + A3[off];
          if (AMODE == 2) pa[i] = avec[kk0 + k] * s;
          else            pa[i] = fmaxf(s + avec[kk0 + k], 0.f);
        }
      }
    }
  };
  auto loadB = [&](int kk0) {
    #pragma unroll
    for (int i = 0; i < NB; ++i) {
      const int idx = tid + i * 256;
      if (BMODE == 0) {
        const int k = idx >> 6, nn = idx & 63;
        pb[i] = (NEXACT || (n0 + nn < N)) ? B[(size_t)(kk0 + k) * N + n0 + nn] : 0.f;
      } else {
        const int k = idx & 63, nn = idx >> 6;
        pb[i] = B[(size_t)(n0 + nn) * K + kk0 + k];
      }
    }
  };
  auto storeAB = [&]() {
    #pragma unroll
    for (int i = 0; i < NA; ++i) {
      const int idx = tid + i * 256;
      if (AMODE == 1) { const int k = idx >> 5, mm = idx & 31; As[k * LDA + mm] = pa[i]; }
      else            { const int k = idx & 63, mm = idx >> 6; As[k * LDA + mm] = pa[i]; }
    }
    #pragma unroll
    for (int i = 0; i < NB; ++i) {
      const int idx = tid + i * 256;
      if (BMODE == 0) { const int k = idx >> 6, nn = idx & 63; Bs[k * LDB + nn] = pb[i]; }
      else            { const int k = idx & 63, nn = idx >> 6; Bs[k * LDB + nn] = pb[i]; }
    }
  };

  loadA(k0); loadB(k0);
  for (int ts = 0; ts < nsteps; ++ts) {
    storeAB();
    __syncthreads();
    if (ts + 1 < nsteps) { loadA(k0 + (ts + 1) * 64); loadB(k0 + (ts + 1) * 64); }
    #pragma unroll
    for (int k = 0; k < 64; ++k) {
      const float2 av = *reinterpret_cast<const float2*>(As + k * LDA + ty * 2);
      const float4 bv = *reinterpret_cast<const float4*>(Bs + k * LDB + tx * 4);
      acc[0][0] += av.x * bv.x; acc[0][1] += av.x * bv.y;
      acc[0][2] += av.x * bv.z; acc[0][3] += av.x * bv.w;
      acc[1][0] += av.y * bv.x; acc[1][1] += av.y * bv.y;
      acc[1][2] += av.y * bv.z; acc[1][3] += av.y * bv.w;
    }
    __syncthreads();
  }

  #pragma unroll
  for (int i = 0; i < 2; ++i) {
    const int mm = m0 + ty * 2 + i;
    #pragma unroll
    for (int j = 0; j < 4; ++j) {
      const int nn = n0 + tx * 4 + j;
      if (NEXACT || nn < N) {
        float v = acc[i][j];
        if (BIAS1) v += bias1[nn];
        C[(size_t)mm * N + nn] = v;
      }
    }
  }
}

// ---- NEW GEMM body (TM4xTN4, 64x64 tile, BK=64, 256 thr, reg-prefetch) ----
// Per k: 2x ds_read_b128 (a 4-way broadcast, b 2-way) for 16 FMAs.
// AMODE: 0 A[m][k]; 1 A^T stored [k][M]; 2 A=gh[k]*(A0+..+A3)[m][k];
//        3 A=relu((A0..A3 sum)[m][k]+avec[k]).  BMODE: 0 B[k][n]; 1 B[n][k].
template <int AMODE, int BMODE>
__device__ __forceinline__ void gemm_body4(
    const float* __restrict__ A0, const float* __restrict__ A1,
    const float* __restrict__ A2, const float* __restrict__ A3,
    const float* __restrict__ avec, const float* __restrict__ B,
    float* __restrict__ C,
    int M, int N, int K, int m0, int n0, int k0, int nsteps,
    float* As, float* Bs) {
  constexpr int LD = 68, NA = 16, NB = 16;
  const int tid = threadIdx.x;
  const int tx = tid & 15, ty = tid >> 4;
  float acc[4][4];
  #pragma unroll
  for (int i = 0; i < 4; ++i)
    #pragma unroll
    for (int j = 0; j < 4; ++j) acc[i][j] = 0.f;
  float pa[NA], pb[NB];

  auto loadA = [&](int kk0) {
    #pragma unroll
    for (int i = 0; i < NA; ++i) {
      const int idx = tid + i * 256;
      if (AMODE == 1) {
        const int k = idx >> 6, mm = idx & 63;
        pa[i] = A0[(size_t)(kk0 + k) * M + m0 + mm];
      } else {
        const int k = idx & 63, mm = idx >> 6;
        const size_t off = (size_t)(m0 + mm) * K + kk0 + k;
        if (AMODE == 0) {
          pa[i] = A0[off];
        } else {
          float s = A0[off] + A1[off] + A2[off] + A3[off];
          if (AMODE == 2) pa[i] = avec[kk0 + k] * s;
          else            pa[i] = fmaxf(s + avec[kk0 + k], 0.f);
        }
      }
    }
  };
  auto loadB = [&](int kk0) {
    #pragma unroll
    for (int i = 0; i < NB; ++i) {
      const int idx = tid + i * 256;
      if (BMODE == 0) {
        const int k = idx >> 6, nn = idx & 63;
        pb[i] = B[(size_t)(kk0 + k) * N + n0 + nn];
      } else {
        const int k = idx & 63, nn = idx >> 6;
        pb[i] = B[(size_t)(n0 + nn) * K + kk0 + k];
      }
    }
  };
  auto storeAB = [&]() {
    #pragma unroll
    for (int i = 0; i < NA; ++i) {
      const int idx = tid + i * 256;
      if (AMODE == 1) { const int k = idx >> 6, mm = idx & 63; As[k * LD + mm] = pa[i]; }
      else            { const int k = idx & 63, mm = idx >> 6; As[k * LD + mm] = pa[i]; }
    }
    #pragma unroll
    for (int i = 0; i < NB; ++i) {
      const int idx = tid + i * 256;
      if (BMODE == 0) { const int k = idx >> 6, nn = idx & 63; Bs[k * LD + nn] = pb[i]; }
      else            { const int k = idx & 63, nn = idx >> 6; Bs[k * LD + nn] = pb[i]; }
    }
  };

  loadA(k0); loadB(k0);
  for (int ts = 0; ts < nsteps; ++ts) {
    storeAB();
    __syncthreads();
    if (ts + 1 < nsteps) { loadA(k0 + (ts + 1) * 64); loadB(k0 + (ts + 1) * 64); }
    #pragma unroll
    for (int k = 0; k < 64; ++k) {
      const float4 av = *reinterpret_cast<const float4*>(As + k * LD + ty * 4);
      const float4 bv = *reinterpret_cast<const float4*>(Bs + k * LD + tx * 4);
      const float a4[4] = {av.x, av.y, av.z, av.w};
      const float b4[4] = {bv.x, bv.y, bv.z, bv.w};
      #pragma unroll
      for (int i = 0; i < 4; ++i)
        #pragma unroll
        for (int j = 0; j < 4; ++j) acc[i][j] += a4[i] * b4[j];
    }
    __syncthreads();
  }

  #pragma unroll
  for (int i = 0; i < 4; ++i) {
    const int mm = m0 + ty * 4 + i;
    float4 v; v.x = acc[i][0]; v.y = acc[i][1]; v.z = acc[i][2]; v.w = acc[i][3];
    st4(C + (size_t)mm * N + n0 + tx * 4, v);
  }
}

#define GEMM_LDS __shared__ float As[64 * 68]; __shared__ float Bs[64 * 68]

// ---- sprl: SpT partials (W_enc^T @ enc) + RL partials (tagH @ W_tag) ------
// 512 blocks, 64x64 tiles, split-K=4 both (chunk 128, nsteps 2).
__global__ __launch_bounds__(256) void sprl2(
    const float* __restrict__ enc, const float* __restrict__ W_enc,
    const float* __restrict__ tagH, const float* __restrict__ W_tag,
    float* __restrict__ PS, float* __restrict__ PR) {
  GEMM_LDS;
  const int b = blockIdx.x;
  if (b < 256) {       // SpT: M=256(a) N=1024(p) K=512(c): 4x16 tiles
    const int tile = b & 63, c = b >> 6;
    const int mi = tile & 3, ni = tile >> 2;
    gemm_body4<1, 0>(W_enc, nullptr, nullptr, nullptr, nullptr, enc,
        PS + c * 262144, 256, 1024, 512, mi * 64, ni * 64, c * 128, 2, As, Bs);
  } else {             // RL: M=1024(n) N=256(a) K=512(d): 16x4 tiles
    const int r = b - 256, tile = r & 63, c = r >> 6;
    const int mi = tile >> 2, ni = tile & 3;
    gemm_body4<0, 0>(tagH, nullptr, nullptr, nullptr, nullptr, W_tag,
        PR + c * 262144, 1024, 256, 512, mi * 64, ni * 64, c * 128, 2, As, Bs);
  }
}

// ---- merge partials once: Sp = sum4(PS);  RLm = sum4(PR)+b_enc+b_tag+Lv ---
__global__ void merge_k(const float* __restrict__ PS, const float* __restrict__ PR,
                        const float* __restrict__ b_enc, const float* __restrict__ b_tag,
                        const float* __restrict__ Lv, float* __restrict__ Sp,
                        float* __restrict__ RLm) {
  const int b = blockIdx.x, t = threadIdx.x;
  if (b < 256) {
    const size_t a = ((size_t)b * 256 + t) * 4;
    float4 s0 = ld4(PS + a), s1 = ld4(PS + 262144 + a);
    float4 s2 = ld4(PS + 524288 + a), s3 = ld4(PS + 786432 + a);
    float4 o;
    o.x = (s0.x + s1.x) + (s2.x + s3.x);
    o.y = (s0.y + s1.y) + (s2.y + s3.y);
    o.z = (s0.z + s1.z) + (s2.z + s3.z);
    o.w = (s0.w + s1.w) + (s2.w + s3.w);
    st4(Sp + a, o);
  } else {
    const size_t i = (size_t)(b - 256) * 256 + t;
    const size_t a = i * 4;
    const int a4 = (int)(i & 63) * 4;
    float4 s0 = ld4(PR + a), s1 = ld4(PR + 262144 + a);
    float4 s2 = ld4(PR + 524288 + a), s3 = ld4(PR + 786432 + a);
    const float4 be = ld4(b_enc + a4), bt = ld4(b_tag + a4), lv = ld4(Lv + a4);
    float4 o;
    o.x = (s0.x + s1.x) + (s2.x + s3.x) + be.x + bt.x + lv.x;
    o.y = (s0.y + s1.y) + (s2.y + s3.y) + be.y + bt.y + lv.y;
    o.z = (s0.z + s1.z) + (s2.z + s3.z) + be.z + bt.z + lv.z;
    o.w = (s0.w + s1.w) + (s2.w + s3.w) + be.w + bt.w + lv.w;
    st4(RLm + a, o);
  }
}

// ---- score v4: Zp[h][n][p] = sum_{a in half h} relu(RLm[n][a]+Sp[a][p])*w[a]
__global__ __launch_bounds__(256) void score4(
    const float* __restrict__ Sp, const float* __restrict__ RLm,
    const float* __restrict__ wfull, float* __restrict__ Zp) {
  __shared__ float spS[32][132];
  __shared__ float rlS[16][132];
  __shared__ float wS[128];
  const int b = blockIdx.x;
  const int h = b & 1, pt = (b >> 1) & 7, nt = b >> 4;
  const int n0 = nt * 16, p0 = pt * 128, a0 = h * 128;
  const int t = threadIdx.x, tx = t & 31, ty = t >> 5;

  {
    const int nn = t >> 4, ag = (t & 15) * 8;
    const float* src = RLm + (size_t)(n0 + nn) * 256 + a0 + ag;
    st4(&rlS[nn][ag], ld4(src));
    st4(&rlS[nn][ag + 4], ld4(src + 4));
  }
  if (t < 128) wS[t] = wfull[a0 + t];

  float4 pf[4];
  auto ldsp = [&](int ac) {
    #pragma unroll
    for (int i = 0; i < 4; ++i) {
      const int idx = t + i * 256;
      const int ar = idx >> 5, pc = (idx & 31) << 2;
      pf[i] = ld4(Sp + (size_t)(a0 + ac * 32 + ar) * 1024 + p0 + pc);
    }
  };

  float z[2][4] = {{0.f, 0.f, 0.f, 0.f}, {0.f, 0.f, 0.f, 0.f}};
  ldsp(0);
  for (int ac = 0; ac < 4; ++ac) {
    __syncthreads();
    #pragma unroll
    for (int i = 0; i < 4; ++i) {
      const int idx = t + i * 256;
      const int ar = idx >> 5, pc = (idx & 31) << 2;
      st4(&spS[ar][pc], pf[i]);
    }
    __syncthreads();
    if (ac < 3) ldsp(ac + 1);
    const int abase = ac * 32;
    #pragma unroll 8
    for (int al = 0; al < 32; ++al) {
      const float w = wS[abase + al];
      const float r0 = rlS[ty * 2][abase + al];
      const float r1 = rlS[ty * 2 + 1][abase + al];
      const float4 s = ld4(&spS[al][tx * 4]);
      z[0][0] += fmaxf(r0 + s.x, 0.f) * w;
      z[0][1] += fmaxf(r0 + s.y, 0.f) * w;
      z[0][2] += fmaxf(r0 + s.z, 0.f) * w;
      z[0][3] += fmaxf(r0 + s.w, 0.f) * w;
      z[1][0] += fmaxf(r1 + s.x, 0.f) * w;
      z[1][1] += fmaxf(r1 + s.y, 0.f) * w;
      z[1][2] += fmaxf(r1 + s.z, 0.f) * w;
      z[1][3] += fmaxf(r1 + s.w, 0.f) * w;
    }
  }

  #pragma unroll
  for (int i = 0; i < 2; ++i) {
    float4 o; o.x = z[i][0]; o.y = z[i][1]; o.z = z[i][2]; o.w = z[i][3];
    st4(Zp + (size_t)h * 1048576 + (size_t)(n0 + ty * 2 + i) * 1024 + p0 + tx * 4, o);
  }
}

// ---- softmax over p per n-row; sums the 2 Z halves ------------------------
__global__ __launch_bounds__(256) void softmax_k(const float* __restrict__ Zp,
                                                 float* __restrict__ alpha) {
  const int n = blockIdx.x, t = threadIdx.x;
  __shared__ float redm[4];
  __shared__ float reds[4];
  const size_t off = (size_t)n * 1024 + 4 * t;
  float4 z = ld4(Zp + off);
  const float4 a1 = ld4(Zp + 1048576 + off);
  z.x += a1.x; z.y += a1.y; z.z += a1.z; z.w += a1.w;
  float m = fmaxf(fmaxf(z.x, z.y), fmaxf(z.z, z.w));
  #pragma unroll
  for (int o = 32; o; o >>= 1) m = fmaxf(m, __shfl_xor(m, o));
  if ((t & 63) == 0) redm[t >> 6] = m;
  __syncthreads();
  m = fmaxf(fmaxf(redm[0], redm[1]), fmaxf(redm[2], redm[3]));
  z.x = __expf(z.x - m); z.y = __expf(z.y - m);
  z.z = __expf(z.z - m); z.w = __expf(z.w - m);
  float s = z.x + z.y + z.z + z.w;
  #pragma unroll
  for (int o = 32; o; o >>= 1) s += __shfl_xor(s, o);
  if ((t & 63) == 0) reds[t >> 6] = s;
  __syncthreads();
  s = reds[0] + reds[1] + reds[2] + reds[3];
  const float inv = 1.f / s;
  z.x *= inv; z.y *= inv; z.z *= inv; z.w *= inv;
  st4(alpha + off, z);
}

// ---- awe partials: PH[c] = alpha @ enc_flat (K-chunk c) -------------------
// 512 blocks, 64x64 tiles, split-K=4 (chunk 256, nsteps 4).
__global__ __launch_bounds__(256) void awe2(const float* __restrict__ alpha,
                                            const float* __restrict__ enc,
                                            float* __restrict__ PH) {
  GEMM_LDS;
  const int b = blockIdx.x, c = b >> 7, tile = b & 127;
  const int mi = tile >> 3, ni = tile & 7;   // 16 x 8 tiles
  gemm_body4<0, 1>(alpha, nullptr, nullptr, nullptr, nullptr, enc,
      PH + c * 524288, 1024, 512, 1024, mi * 64, ni * 64, c * 256, 4, As, Bs);
}

// ---- cls (blocks 0..31, TM2 body) + m1 partials (TM4, 64x64) --------------
__global__ __launch_bounds__(256) void m1cls2(
    const float* __restrict__ PH, const float* __restrict__ gh,
    const float* __restrict__ W_m1, const float* __restrict__ W_cls,
    const float* __restrict__ b_cls, float* __restrict__ PX1,
    float* __restrict__ out) {
  GEMM_LDS;
  const int b = blockIdx.x;
  if (b < 32) {        // cls: M=1024 N=31 K=512, no split (8 steps), TM2 body
    const int mi = b;
    gemm_body2<2, 0, true, false>(PH, PH + 524288, PH + 1048576, PH + 1572864, gh,
        W_cls, b_cls, out, 1024, 31, 512, mi * 32, 0, 0, 8, As, Bs);
  } else {             // m1: M=1024 N=256 K=512: 16x4 tiles, split-K=4
    const int r = b - 32, c = r >> 6, tile = r & 63;
    const int mi = tile >> 2, ni = tile & 3;
    gemm_body4<2, 0>(PH, PH + 524288, PH + 1048576, PH + 1572864, gh,
        W_m1, PX1 + c * 262144, 1024, 256, 512, mi * 64, ni * 64, c * 128, 2, As, Bs);
  }
}

// ---- m2 partials; A = relu(sum4(PX1) + b_m1[k]) ---------------------------
// 256 blocks: 16x4 tiles x split-K=4 (chunk 64, nsteps 1).
__global__ __launch_bounds__(256) void m2k(
    const float* __restrict__ PX1, const float* __restrict__ b_m1,
    const float* __restrict__ W_m2, float* __restrict__ PX2) {
  GEMM_LDS;
  const int b = blockIdx.x;
  const int c = b >> 6, tile = b & 63, mi = tile >> 2, ni = tile & 3;
  gemm_body4<3, 0>(PX1, PX1 + 262144, PX1 + 524288, PX1 + 786432, b_m1,
      W_m2, PX2 + c * 262144, 1024, 256, 256, mi * 64, ni * 64, c * 64, 1, As, Bs);
}

// ---- boxes = sigmoid(relu(sum4(PX2)+b_m2) @ W3 + b3) ----------------------
__global__ __launch_bounds__(256) void m3k(
    const float* __restrict__ PX2, const float* __restrict__ b_m2,
    const float* __restrict__ W3, const float* __restrict__ b3,
    float* __restrict__ out2) {
  __shared__ float xr[8 * 260];
  __shared__ float w3s[1024];
  const int t = threadIdx.x, m0 = blockIdx.x * 8;
  #pragma unroll
  for (int ml = 0; ml < 8; ++ml) {
    const size_t off = (size_t)(m0 + ml) * 256 + t;
    const float s = PX2[off] + PX2[262144 + off] + PX2[524288 + off] + PX2[786432 + off]
                  + b_m2[t];
    xr[ml * 260 + t] = fmaxf(s, 0.f);
  }
  for (int i = t; i < 1024; i += 256) w3s[i] = W3[i];
  __syncthreads();
  if (t < 32) {
    const int ml = t >> 2, nn = t & 3;
    float acc = b3[nn];
    #pragma unroll 8
    for (int k = 0; k < 256; ++k) acc += xr[ml * 260 + k] * w3s[k * 4 + nn];
    out2[(size_t)(m0 + ml) * 4 + nn] = 1.f / (1.f + __expf(-acc));
  }
}

// ---------------------------------------------------------------------------
extern "C" void kernel_launch(void* const* d_in, const int* in_sizes, int n_in,
                              void* d_out, int out_size, void* d_ws, size_t ws_size,
                              hipStream_t stream) {
  const float* enc     = (const float*)d_in[0];
  const float* tagH    = (const float*)d_in[1];
  const float* W_enc   = (const float*)d_in[2];
  const float* b_enc   = (const float*)d_in[3];
  const float* W_tag   = (const float*)d_in[4];
  const float* b_tag   = (const float*)d_in[5];
  const float* W_lang  = (const float*)d_in[6];
  const float* b_lang  = (const float*)d_in[7];
  const float* w_full  = (const float*)d_in[8];
  // d_in[9] = b_full: softmax shift-invariant, unused
  const float* W_init  = (const float*)d_in[10];
  const float* b_init  = (const float*)d_in[11];
  const float* W_fbeta = (const float*)d_in[12];
  const float* b_fbeta = (const float*)d_in[13];
  const float* W_cls   = (const float*)d_in[14];
  const float* b_cls   = (const float*)d_in[15];
  const float* W_m1    = (const float*)d_in[16];
  const float* b_m1    = (const float*)d_in[17];
  const float* W_m2    = (const float*)d_in[18];
  const float* b_m2    = (const float*)d_in[19];
  const float* W_m3    = (const float*)d_in[20];
  const float* b_m3    = (const float*)d_in[21];
  float* out = (float*)d_out;

  // workspace (floats); aliases stream-ordered, every region written before
  // read each call (layout identical to R8):
  float* ws    = (float*)d_ws;
  float* PS    = ws;                     // [4][256][1024]
  float* PR    = ws + 1048576;           // [4][1024][256]
  float* alpha = ws;                     // [1024][1024]
  float* PX2   = ws;                     // [4][1024][256]
  float* PX1   = ws + 1048576;           // [4][1024][256]
  float* Sp    = ws + 2097152;           // [256][1024]
  float* RLm   = ws + 2359296;           // [1024][256]
  float* Zp    = ws + 2621440;           // [2][1024][1024]
  float* PH    = ws + 2621440;           // [4][1024][512]
  float* meanv = ws + 4718592;           // [512]
  float* h0v   = ws + 4719104;           // [512]
  float* Lv    = ws + 4719616;           // [256]
  float* gh    = ws + 4719872;           // [512]

  mean_kernel<<<512, 256, 0, stream>>>(enc, meanv);
  h0_k<<<16, 256, 0, stream>>>(meanv, W_init, b_init, h0v);
  ghL_k<<<24, 256, 0, stream>>>(h0v, W_fbeta, b_fbeta, W_lang, b_lang, gh, Lv);
  sprl2<<<512, 256, 0, stream>>>(enc, W_enc, tagH, W_tag, PS, PR);
  merge_k<<<512, 256, 0, stream>>>(PS, PR, b_enc, b_tag, Lv, Sp, RLm);
  score4<<<1024, 256, 0, stream>>>(Sp, RLm, w_full, Zp);
  softmax_k<<<1024, 256, 0, stream>>>(Zp, alpha);
  awe2<<<512, 256, 0, stream>>>(alpha, enc, PH);
  m1cls2<<<288, 256, 0, stream>>>(PH, gh, W_m1, W_cls, b_cls, PX1, out);
  m2k<<<256, 256, 0, stream>>>(PX1, b_m1, W_m2, PX2);
  m3k<<<128, 256, 0, stream>>>(PX2, b_m2, W_m3, b_m3, out + 31744);
}

// Round 11
// 209.130 us; speedup vs baseline: 1.0728x; 1.0728x over previous
//
#include <hip/hip_runtime.h>
#include <math.h>

// ---------------------------------------------------------------------------
// BBoxDecoder fp32, round 11 (= round 10 resubmitted; R10 bench was an infra
// failure).  P=1024, C=512, A=256, D=512, N=1024, NC=30.
//   enc stored [C][P]  => enc_flat[p][c] = enc[c*1024+p]
// R9 profile: sprl2 TM4@512blk regressed to 49us (Occ 9.8% - wave-count
// bound, 2 blk/CU below the ~16 waves/CU latency-hiding threshold); TM4 on
// awe/m1/m2 netted ~-4us.  Fix: revert sprl to TM2@1024 + fuse mean branch;
// cls split-K=2 (kills m1cls straggler tail, reduce in m3k); 10 dispatches.
// ---------------------------------------------------------------------------

__device__ __forceinline__ float4 ld4(const float* p) {
  return *reinterpret_cast<const float4*>(p);
}
__device__ __forceinline__ void st4(float* p, float4 v) {
  *reinterpret_cast<float4*>(p) = v;
}

// ---- h0[d] = mean @ W_init + b_init.  16 blocks x 32 outputs --------------
__global__ __launch_bounds__(256) void h0_k(
    const float* __restrict__ mean, const float* __restrict__ W_init,
    const float* __restrict__ b_init, float* __restrict__ h0) {
  __shared__ float ms[512];
  __shared__ float red[8][33];
  const int t = threadIdx.x;
  ms[t] = mean[t]; ms[t + 256] = mean[t + 256];
  __syncthreads();
  const int d0 = blockIdx.x * 32, dl = t & 31, cg = t >> 5;
  float acc = 0.f;
  #pragma unroll 8
  for (int c = cg * 64; c < cg * 64 + 64; ++c)
    acc += ms[c] * W_init[c * 512 + d0 + dl];
  red[cg][dl] = acc;
  __syncthreads();
  if (t < 32) {
    const float s = red[0][t] + red[1][t] + red[2][t] + red[3][t]
                  + red[4][t] + red[5][t] + red[6][t] + red[7][t];
    h0[d0 + t] = s + b_init[d0 + t];
  }
}

// ---- gh[c] = sigmoid(h0@W_fbeta+b_fbeta)[c]*h0[c];  L[a] = h0@W_lang+b_lang
__global__ __launch_bounds__(256) void ghL_k(
    const float* __restrict__ h0, const float* __restrict__ W_fbeta,
    const float* __restrict__ b_fbeta, const float* __restrict__ W_lang,
    const float* __restrict__ b_lang, float* __restrict__ gh,
    float* __restrict__ Lv) {
  __shared__ float hs[512];
  __shared__ float red[8][33];
  const int t = threadIdx.x;
  hs[t] = h0[t]; hs[t + 256] = h0[t + 256];
  __syncthreads();
  const int b = blockIdx.x, ol = t & 31, cg = t >> 5;
  if (b < 16) {
    const int c0 = b * 32;
    float acc = 0.f;
    #pragma unroll 8
    for (int d = cg * 64; d < cg * 64 + 64; ++d)
      acc += hs[d] * W_fbeta[d * 512 + c0 + ol];
    red[cg][ol] = acc;
    __syncthreads();
    if (t < 32) {
      const int c = c0 + t;
      const float s = red[0][t] + red[1][t] + red[2][t] + red[3][t]
                    + red[4][t] + red[5][t] + red[6][t] + red[7][t] + b_fbeta[c];
      gh[c] = hs[c] / (1.f + __expf(-s));
    }
  } else {
    const int a0 = (b - 16) * 32;
    float acc = 0.f;
    #pragma unroll 8
    for (int d = cg * 64; d < cg * 64 + 64; ++d)
      acc += hs[d] * W_lang[d * 256 + a0 + ol];
    red[cg][ol] = acc;
    __syncthreads();
    if (t < 32) {
      const float s = red[0][t] + red[1][t] + red[2][t] + red[3][t]
                    + red[4][t] + red[5][t] + red[6][t] + red[7][t];
      Lv[a0 + t] = s + b_lang[a0 + t];
    }
  }
}

// ---- GEMM body TM2xTN4 (32x64 tile, BK=64, reg-prefetch) ------------------
// AMODE: 0 A[m][k]; 1 A^T stored [k][M]; 2 A=gh[k]*(A0+..+A3)[m][k];
//        3 A=relu((A0..A3 sum)[m][k]+avec[k]).  BMODE: 0 B[k][n]; 1 B[n][k].
template <int AMODE, int BMODE, bool BIAS1, bool NEXACT>
__device__ __forceinline__ void gemm_body2(
    const float* __restrict__ A0, const float* __restrict__ A1,
    const float* __restrict__ A2, const float* __restrict__ A3,
    const float* __restrict__ avec, const float* __restrict__ B,
    const float* __restrict__ bias1, float* __restrict__ C,
    int M, int N, int K, int m0, int n0, int k0, int nsteps,
    float* As, float* Bs) {
  constexpr int LDA = 36, LDB = 68, NA = 8, NB = 16;
  const int tid = threadIdx.x;
  const int tx = tid & 15, ty = tid >> 4;
  float acc[2][4] = {{0.f, 0.f, 0.f, 0.f}, {0.f, 0.f, 0.f, 0.f}};
  float pa[NA], pb[NB];

  auto loadA = [&](int kk0) {
    #pragma unroll
    for (int i = 0; i < NA; ++i) {
      const int idx = tid + i * 256;
      if (AMODE == 1) {
        const int k = idx >> 5, mm = idx & 31;
        pa[i] = A0[(size_t)(kk0 + k) * M + m0 + mm];
      } else {
        const int k = idx & 63, mm = idx >> 6;
        const size_t off = (size_t)(m0 + mm) * K + kk0 + k;
        if (AMODE == 0) {
          pa[i] = A0[off];
        } else {
          float s = A0[off] + A1[off] + A2[off] + A3[off];
          if (AMODE == 2) pa[i] = avec[kk0 + k] * s;
          else            pa[i] = fmaxf(s + avec[kk0 + k], 0.f);
        }
      }
    }
  };
  auto loadB = [&](int kk0) {
    #pragma unroll
    for (int i = 0; i < NB; ++i) {
      const int idx = tid + i * 256;
      if (BMODE == 0) {
        const int k = idx >> 6, nn = idx & 63;
        pb[i] = (NEXACT || (n0 + nn < N)) ? B[(size_t)(kk0 + k) * N + n0 + nn] : 0.f;
      } else {
        const int k = idx & 63, nn = idx >> 6;
        pb[i] = B[(size_t)(n0 + nn) * K + kk0 + k];
      }
    }
  };
  auto storeAB = [&]() {
    #pragma unroll
    for (int i = 0; i < NA; ++i) {
      const int idx = tid + i * 256;
      if (AMODE == 1) { const int k = idx >> 5, mm = idx & 31; As[k * LDA + mm] = pa[i]; }
      else            { const int k = idx & 63, mm = idx >> 6; As[k * LDA + mm] = pa[i]; }
    }
    #pragma unroll
    for (int i = 0; i < NB; ++i) {
      const int idx = tid + i * 256;
      if (BMODE == 0) { const int k = idx >> 6, nn = idx & 63; Bs[k * LDB + nn] = pb[i]; }
      else            { const int k = idx & 63, nn = idx >> 6; Bs[k * LDB + nn] = pb[i]; }
    }
  };

  loadA(k0); loadB(k0);
  for (int ts = 0; ts < nsteps; ++ts) {
    storeAB();
    __syncthreads();
    if (ts + 1 < nsteps) { loadA(k0 + (ts + 1) * 64); loadB(k0 + (ts + 1) * 64); }
    #pragma unroll
    for (int k = 0; k < 64; ++k) {
      const float2 av = *reinterpret_cast<const float2*>(As + k * LDA + ty * 2);
      const float4 bv = *reinterpret_cast<const float4*>(Bs + k * LDB + tx * 4);
      acc[0][0] += av.x * bv.x; acc[0][1] += av.x * bv.y;
      acc[0][2] += av.x * bv.z; acc[0][3] += av.x * bv.w;
      acc[1][0] += av.y * bv.x; acc[1][1] += av.y * bv.y;
      acc[1][2] += av.y * bv.z; acc[1][3] += av.y * bv.w;
    }
    __syncthreads();
  }

  #pragma unroll
  for (int i = 0; i < 2; ++i) {
    const int mm = m0 + ty * 2 + i;
    #pragma unroll
    for (int j = 0; j < 4; ++j) {
      const int nn = n0 + tx * 4 + j;
      if (NEXACT || nn < N) {
        float v = acc[i][j];
        if (BIAS1) v += bias1[nn];
        C[(size_t)mm * N + nn] = v;
      }
    }
  }
}

// ---- GEMM body TM4xTN4 (64x64 tile, BK=64, reg-prefetch) ------------------
template <int AMODE, int BMODE>
__device__ __forceinline__ void gemm_body4(
    const float* __restrict__ A0, const float* __restrict__ A1,
    const float* __restrict__ A2, const float* __restrict__ A3,
    const float* __restrict__ avec, const float* __restrict__ B,
    float* __restrict__ C,
    int M, int N, int K, int m0, int n0, int k0, int nsteps,
    float* As, float* Bs) {
  constexpr int LD = 68, NA = 16, NB = 16;
  const int tid = threadIdx.x;
  const int tx = tid & 15, ty = tid >> 4;
  float acc[4][4];
  #pragma unroll
  for (int i = 0; i < 4; ++i)
    #pragma unroll
    for (int j = 0; j < 4; ++j) acc[i][j] = 0.f;
  float pa[NA], pb[NB];

  auto loadA = [&](int kk0) {
    #pragma unroll
    for (int i = 0; i < NA; ++i) {
      const int idx = tid + i * 256;
      if (AMODE == 1) {
        const int k = idx >> 6, mm = idx & 63;
        pa[i] = A0[(size_t)(kk0 + k) * M + m0 + mm];
      } else {
        const int k = idx & 63, mm = idx >> 6;
        const size_t off = (size_t)(m0 + mm) * K + kk0 + k;
        if (AMODE == 0) {
          pa[i] = A0[off];
        } else {
          float s = A0[off] + A1[off] + A2[off] + A3[off];
          if (AMODE == 2) pa[i] = avec[kk0 + k] * s;
          else            pa[i] = fmaxf(s + avec[kk0 + k], 0.f);
        }
      }
    }
  };
  auto loadB = [&](int kk0) {
    #pragma unroll
    for (int i = 0; i < NB; ++i) {
      const int idx = tid + i * 256;
      if (BMODE == 0) {
        const int k = idx >> 6, nn = idx & 63;
        pb[i] = B[(size_t)(kk0 + k) * N + n0 + nn];
      } else {
        const int k = idx & 63, nn = idx >> 6;
        pb[i] = B[(size_t)(n0 + nn) * K + kk0 + k];
      }
    }
  };
  auto storeAB = [&]() {
    #pragma unroll
    for (int i = 0; i < NA; ++i) {
      const int idx = tid + i * 256;
      if (AMODE == 1) { const int k = idx >> 6, mm = idx & 63; As[k * LD + mm] = pa[i]; }
      else            { const int k = idx & 63, mm = idx >> 6; As[k * LD + mm] = pa[i]; }
    }
    #pragma unroll
    for (int i = 0; i < NB; ++i) {
      const int idx = tid + i * 256;
      if (BMODE == 0) { const int k = idx >> 6, nn = idx & 63; Bs[k * LD + nn] = pb[i]; }
      else            { const int k = idx & 63, nn = idx >> 6; Bs[k * LD + nn] = pb[i]; }
    }
  };

  loadA(k0); loadB(k0);
  for (int ts = 0; ts < nsteps; ++ts) {
    storeAB();
    __syncthreads();
    if (ts + 1 < nsteps) { loadA(k0 + (ts + 1) * 64); loadB(k0 + (ts + 1) * 64); }
    #pragma unroll
    for (int k = 0; k < 64; ++k) {
      const float4 av = *reinterpret_cast<const float4*>(As + k * LD + ty * 4);
      const float4 bv = *reinterpret_cast<const float4*>(Bs + k * LD + tx * 4);
      const float a4[4] = {av.x, av.y, av.z, av.w};
      const float b4[4] = {bv.x, bv.y, bv.z, bv.w};
      #pragma unroll
      for (int i = 0; i < 4; ++i)
        #pragma unroll
        for (int j = 0; j < 4; ++j) acc[i][j] += a4[i] * b4[j];
    }
    __syncthreads();
  }

  #pragma unroll
  for (int i = 0; i < 4; ++i) {
    const int mm = m0 + ty * 4 + i;
    float4 v; v.x = acc[i][0]; v.y = acc[i][1]; v.z = acc[i][2]; v.w = acc[i][3];
    st4(C + (size_t)mm * N + n0 + tx * 4, v);
  }
}

// ---- fused: SpT partials + RL partials (TM2, split-K=4) + mean ------------
// 1536 blocks: [0,512) SpT, [512,1024) RL, [1024,1536) mean.
__global__ __launch_bounds__(256) void sprlmean(
    const float* __restrict__ enc, const float* __restrict__ W_enc,
    const float* __restrict__ tagH, const float* __restrict__ W_tag,
    float* __restrict__ PS, float* __restrict__ PR, float* __restrict__ mean) {
  __shared__ float As[64 * 36];
  __shared__ float Bs[64 * 68];
  const int b = blockIdx.x;
  if (b < 512) {       // SpT: M=256(a) N=1024(p) K=512(c), split-K=4
    const int tile = b & 127, c = b >> 7;
    const int mi = tile & 7, ni = tile >> 3;
    gemm_body2<1, 0, false, true>(W_enc, nullptr, nullptr, nullptr, nullptr, enc,
        nullptr, PS + c * 262144, 256, 1024, 512, mi * 32, ni * 64, c * 128, 2, As, Bs);
  } else if (b < 1024) {  // RL: M=1024(n) N=256(a) K=512(d), split-K=4
    const int r = b - 512, tile = r & 127, c = r >> 7;
    const int mi = tile >> 2, ni = tile & 3;
    gemm_body2<0, 0, false, true>(tagH, nullptr, nullptr, nullptr, nullptr, W_tag,
        nullptr, PR + c * 262144, 1024, 256, 512, mi * 32, ni * 64, c * 128, 2, As, Bs);
  } else {             // mean[c] over P
    const int c = b - 1024, t = threadIdx.x;
    float4 v = reinterpret_cast<const float4*>(enc + (size_t)c * 1024)[t];
    float s = v.x + v.y + v.z + v.w;
    #pragma unroll
    for (int off = 32; off; off >>= 1) s += __shfl_xor(s, off);
    if ((t & 63) == 0) As[t >> 6] = s;
    __syncthreads();
    if (t == 0) mean[c] = (As[0] + As[1] + As[2] + As[3]) * (1.0f / 1024.0f);
  }
}

// ---- merge partials once: Sp = sum4(PS);  RLm = sum4(PR)+b_enc+b_tag+Lv ---
__global__ void merge_k(const float* __restrict__ PS, const float* __restrict__ PR,
                        const float* __restrict__ b_enc, const float* __restrict__ b_tag,
                        const float* __restrict__ Lv, float* __restrict__ Sp,
                        float* __restrict__ RLm) {
  const int b = blockIdx.x, t = threadIdx.x;
  if (b < 256) {
    const size_t a = ((size_t)b * 256 + t) * 4;
    float4 s0 = ld4(PS + a), s1 = ld4(PS + 262144 + a);
    float4 s2 = ld4(PS + 524288 + a), s3 = ld4(PS + 786432 + a);
    float4 o;
    o.x = (s0.x + s1.x) + (s2.x + s3.x);
    o.y = (s0.y + s1.y) + (s2.y + s3.y);
    o.z = (s0.z + s1.z) + (s2.z + s3.z);
    o.w = (s0.w + s1.w) + (s2.w + s3.w);
    st4(Sp + a, o);
  } else {
    const size_t i = (size_t)(b - 256) * 256 + t;
    const size_t a = i * 4;
    const int a4 = (int)(i & 63) * 4;
    float4 s0 = ld4(PR + a), s1 = ld4(PR + 262144 + a);
    float4 s2 = ld4(PR + 524288 + a), s3 = ld4(PR + 786432 + a);
    const float4 be = ld4(b_enc + a4), bt = ld4(b_tag + a4), lv = ld4(Lv + a4);
    float4 o;
    o.x = (s0.x + s1.x) + (s2.x + s3.x) + be.x + bt.x + lv.x;
    o.y = (s0.y + s1.y) + (s2.y + s3.y) + be.y + bt.y + lv.y;
    o.z = (s0.z + s1.z) + (s2.z + s3.z) + be.z + bt.z + lv.z;
    o.w = (s0.w + s1.w) + (s2.w + s3.w) + be.w + bt.w + lv.w;
    st4(RLm + a, o);
  }
}

// ---- score v4: Zp[h][n][p] = sum_{a in half h} relu(RLm[n][a]+Sp[a][p])*w[a]
__global__ __launch_bounds__(256) void score4(
    const float* __restrict__ Sp, const float* __restrict__ RLm,
    const float* __restrict__ wfull, float* __restrict__ Zp) {
  __shared__ float spS[32][132];
  __shared__ float rlS[16][132];
  __shared__ float wS[128];
  const int b = blockIdx.x;
  const int h = b & 1, pt = (b >> 1) & 7, nt = b >> 4;
  const int n0 = nt * 16, p0 = pt * 128, a0 = h * 128;
  const int t = threadIdx.x, tx = t & 31, ty = t >> 5;

  {
    const int nn = t >> 4, ag = (t & 15) * 8;
    const float* src = RLm + (size_t)(n0 + nn) * 256 + a0 + ag;
    st4(&rlS[nn][ag], ld4(src));
    st4(&rlS[nn][ag + 4], ld4(src + 4));
  }
  if (t < 128) wS[t] = wfull[a0 + t];

  float4 pf[4];
  auto ldsp = [&](int ac) {
    #pragma unroll
    for (int i = 0; i < 4; ++i) {
      const int idx = t + i * 256;
      const int ar = idx >> 5, pc = (idx & 31) << 2;
      pf[i] = ld4(Sp + (size_t)(a0 + ac * 32 + ar) * 1024 + p0 + pc);
    }
  };

  float z[2][4] = {{0.f, 0.f, 0.f, 0.f}, {0.f, 0.f, 0.f, 0.f}};
  ldsp(0);
  for (int ac = 0; ac < 4; ++ac) {
    __syncthreads();
    #pragma unroll
    for (int i = 0; i < 4; ++i) {
      const int idx = t + i * 256;
      const int ar = idx >> 5, pc = (idx & 31) << 2;
      st4(&spS[ar][pc], pf[i]);
    }
    __syncthreads();
    if (ac < 3) ldsp(ac + 1);
    const int abase = ac * 32;
    #pragma unroll 8
    for (int al = 0; al < 32; ++al) {
      const float w = wS[abase + al];
      const float r0 = rlS[ty * 2][abase + al];
      const float r1 = rlS[ty * 2 + 1][abase + al];
      const float4 s = ld4(&spS[al][tx * 4]);
      z[0][0] += fmaxf(r0 + s.x, 0.f) * w;
      z[0][1] += fmaxf(r0 + s.y, 0.f) * w;
      z[0][2] += fmaxf(r0 + s.z, 0.f) * w;
      z[0][3] += fmaxf(r0 + s.w, 0.f) * w;
      z[1][0] += fmaxf(r1 + s.x, 0.f) * w;
      z[1][1] += fmaxf(r1 + s.y, 0.f) * w;
      z[1][2] += fmaxf(r1 + s.z, 0.f) * w;
      z[1][3] += fmaxf(r1 + s.w, 0.f) * w;
    }
  }

  #pragma unroll
  for (int i = 0; i < 2; ++i) {
    float4 o; o.x = z[i][0]; o.y = z[i][1]; o.z = z[i][2]; o.w = z[i][3];
    st4(Zp + (size_t)h * 1048576 + (size_t)(n0 + ty * 2 + i) * 1024 + p0 + tx * 4, o);
  }
}

// ---- softmax over p per n-row; sums the 2 Z halves ------------------------
__global__ __launch_bounds__(256) void softmax_k(const float* __restrict__ Zp,
                                                 float* __restrict__ alpha) {
  const int n = blockIdx.x, t = threadIdx.x;
  __shared__ float redm[4];
  __shared__ float reds[4];
  const size_t off = (size_t)n * 1024 + 4 * t;
  float4 z = ld4(Zp + off);
  const float4 a1 = ld4(Zp + 1048576 + off);
  z.x += a1.x; z.y += a1.y; z.z += a1.z; z.w += a1.w;
  float m = fmaxf(fmaxf(z.x, z.y), fmaxf(z.z, z.w));
  #pragma unroll
  for (int o = 32; o; o >>= 1) m = fmaxf(m, __shfl_xor(m, o));
  if ((t & 63) == 0) redm[t >> 6] = m;
  __syncthreads();
  m = fmaxf(fmaxf(redm[0], redm[1]), fmaxf(redm[2], redm[3]));
  z.x = __expf(z.x - m); z.y = __expf(z.y - m);
  z.z = __expf(z.z - m); z.w = __expf(z.w - m);
  float s = z.x + z.y + z.z + z.w;
  #pragma unroll
  for (int o = 32; o; o >>= 1) s += __shfl_xor(s, o);
  if ((t & 63) == 0) reds[t >> 6] = s;
  __syncthreads();
  s = reds[0] + reds[1] + reds[2] + reds[3];
  const float inv = 1.f / s;
  z.x *= inv; z.y *= inv; z.z *= inv; z.w *= inv;
  st4(alpha + off, z);
}

// ---- awe partials: PH[c] = alpha @ enc_flat (TM4, 512 blocks) -------------
__global__ __launch_bounds__(256) void awe2(const float* __restrict__ alpha,
                                            const float* __restrict__ enc,
                                            float* __restrict__ PH) {
  __shared__ float As[64 * 68];
  __shared__ float Bs[64 * 68];
  const int b = blockIdx.x, c = b >> 7, tile = b & 127;
  const int mi = tile >> 3, ni = tile & 7;   // 16 x 8 tiles
  gemm_body4<0, 1>(alpha, nullptr, nullptr, nullptr, nullptr, enc,
      PH + c * 524288, 1024, 512, 1024, mi * 64, ni * 64, c * 256, 4, As, Bs);
}

// ---- cls partials (split-K=2, TM2) + m1 partials (TM4) --------------------
// 320 blocks: [0,64) cls (2 k-chunks x 32 m-tiles), [64,320) m1.
__global__ __launch_bounds__(256) void m1cls2(
    const float* __restrict__ PH, const float* __restrict__ gh,
    const float* __restrict__ W_m1, const float* __restrict__ W_cls,
    float* __restrict__ PX1, float* __restrict__ PC) {
  __shared__ float As[64 * 68];
  __shared__ float Bs[64 * 68];
  const int b = blockIdx.x;
  if (b < 64) {        // cls: M=1024 N=31 K=512, split-K=2 (chunk 256)
    const int c = b >> 5, mi = b & 31;
    gemm_body2<2, 0, false, false>(PH, PH + 524288, PH + 1048576, PH + 1572864, gh,
        W_cls, nullptr, PC + c * 31744, 1024, 31, 512, mi * 32, 0, c * 256, 4, As, Bs);
  } else {             // m1: M=1024 N=256 K=512: TM4, split-K=4 (chunk 128)
    const int r = b - 64, c = r >> 6, tile = r & 63;
    const int mi = tile >> 2, ni = tile & 3;
    gemm_body4<2, 0>(PH, PH + 524288, PH + 1048576, PH + 1572864, gh,
        W_m1, PX1 + c * 262144, 1024, 256, 512, mi * 64, ni * 64, c * 128, 2, As, Bs);
  }
}

// ---- m2 partials; A = relu(sum4(PX1) + b_m1[k])  (TM4, 256 blocks) --------
__global__ __launch_bounds__(256) void m2k(
    const float* __restrict__ PX1, const float* __restrict__ b_m1,
    const float* __restrict__ W_m2, float* __restrict__ PX2) {
  __shared__ float As[64 * 68];
  __shared__ float Bs[64 * 68];
  const int b = blockIdx.x;
  const int c = b >> 6, tile = b & 63, mi = tile >> 2, ni = tile & 3;
  gemm_body4<3, 0>(PX1, PX1 + 262144, PX1 + 524288, PX1 + 786432, b_m1,
      W_m2, PX2 + c * 262144, 1024, 256, 256, mi * 64, ni * 64, c * 64, 1, As, Bs);
}

// ---- boxes + cls reduce ---------------------------------------------------
// blocks [0,128): boxes = sigmoid(relu(sum4(PX2)+b_m2) @ W3 + b3), 8 rows each
// blocks [128,160): out_cls[m][j] = PC0+PC1+b_cls, 32 rows each
__global__ __launch_bounds__(256) void m3k(
    const float* __restrict__ PX2, const float* __restrict__ b_m2,
    const float* __restrict__ W3, const float* __restrict__ b3,
    const float* __restrict__ PC, const float* __restrict__ b_cls,
    float* __restrict__ out_cls, float* __restrict__ out2) {
  const int t = threadIdx.x, b = blockIdx.x;
  if (b < 128) {
    __shared__ float xr[8 * 260];
    __shared__ float w3s[1024];
    const int m0 = b * 8;
    #pragma unroll
    for (int ml = 0; ml < 8; ++ml) {
      const size_t off = (size_t)(m0 + ml) * 256 + t;
      const float s = PX2[off] + PX2[262144 + off] + PX2[524288 + off]
                    + PX2[786432 + off] + b_m2[t];
      xr[ml * 260 + t] = fmaxf(s, 0.f);
    }
    for (int i = t; i < 1024; i += 256) w3s[i] = W3[i];
    __syncthreads();
    if (t < 32) {
      const int ml = t >> 2, nn = t & 3;
      float acc = b3[nn];
      #pragma unroll 8
      for (int k = 0; k < 256; ++k) acc += xr[ml * 260 + k] * w3s[k * 4 + nn];
      out2[(size_t)(m0 + ml) * 4 + nn] = 1.f / (1.f + __expf(-acc));
    }
  } else {
    const int r8 = t >> 5, col = t & 31;
    if (col < 31) {
      const int mbase = (b - 128) * 32;
      #pragma unroll
      for (int i = 0; i < 4; ++i) {
        const int m = mbase + r8 + i * 8;
        out_cls[m * 31 + col] = PC[m * 31 + col] + PC[31744 + m * 31 + col] + b_cls[col];
      }
    }
  }
}

// ---------------------------------------------------------------------------
extern "C" void kernel_launch(void* const* d_in, const int* in_sizes, int n_in,
                              void* d_out, int out_size, void* d_ws, size_t ws_size,
                              hipStream_t stream) {
  const float* enc     = (const float*)d_in[0];
  const float* tagH    = (const float*)d_in[1];
  const float* W_enc   = (const float*)d_in[2];
  const float* b_enc   = (const float*)d_in[3];
  const float* W_tag   = (const float*)d_in[4];
  const float* b_tag   = (const float*)d_in[5];
  const float* W_lang  = (const float*)d_in[6];
  const float* b_lang  = (const float*)d_in[7];
  const float* w_full  = (const float*)d_in[8];
  // d_in[9] = b_full: softmax shift-invariant, unused
  const float* W_init  = (const float*)d_in[10];
  const float* b_init  = (const float*)d_in[11];
  const float* W_fbeta = (const float*)d_in[12];
  const float* b_fbeta = (const float*)d_in[13];
  const float* W_cls   = (const float*)d_in[14];
  const float* b_cls   = (const float*)d_in[15];
  const float* W_m1    = (const float*)d_in[16];
  const float* b_m1    = (const float*)d_in[17];
  const float* W_m2    = (const float*)d_in[18];
  const float* b_m2    = (const float*)d_in[19];
  const float* W_m3    = (const float*)d_in[20];
  const float* b_m3    = (const float*)d_in[21];
  float* out = (float*)d_out;

  // workspace (floats); aliases stream-ordered, every region written before
  // read each call (layout identical to R8/R9 + PC after smalls):
  float* ws    = (float*)d_ws;
  float* PS    = ws;                     // [4][256][1024]
  float* PR    = ws + 1048576;           // [4][1024][256]
  float* alpha = ws;                     // [1024][1024]
  float* PX2   = ws;                     // [4][1024][256]
  float* PX1   = ws + 1048576;           // [4][1024][256]
  float* Sp    = ws + 2097152;           // [256][1024]
  float* RLm   = ws + 2359296;           // [1024][256]
  float* Zp    = ws + 2621440;           // [2][1024][1024]
  float* PH    = ws + 2621440;           // [4][1024][512]
  float* meanv = ws + 4718592;           // [512]
  float* h0v   = ws + 4719104;           // [512]
  float* Lv    = ws + 4719616;           // [256]
  float* gh    = ws + 4719872;           // [512]
  float* PC    = ws + 4720384;           // [2][1024][31]

  sprlmean<<<1536, 256, 0, stream>>>(enc, W_enc, tagH, W_tag, PS, PR, meanv);
  h0_k<<<16, 256, 0, stream>>>(meanv, W_init, b_init, h0v);
  ghL_k<<<24, 256, 0, stream>>>(h0v, W_fbeta, b_fbeta, W_lang, b_lang, gh, Lv);
  merge_k<<<512, 256, 0, stream>>>(PS, PR, b_enc, b_tag, Lv, Sp, RLm);
  score4<<<1024, 256, 0, stream>>>(Sp, RLm, w_full, Zp);
  softmax_k<<<1024, 256, 0, stream>>>(Zp, alpha);
  awe2<<<512, 256, 0, stream>>>(alpha, enc, PH);
  m1cls2<<<320, 256, 0, stream>>>(PH, gh, W_m1, W_cls, PX1, PC);
  m2k<<<256, 256, 0, stream>>>(PX1, b_m1, W_m2, PX2);
  m3k<<<160, 256, 0, stream>>>(PX2, b_m2, W_m3, b_m3, PC, b_cls, out, out + 31744);
}